// Round 1
// baseline (15.545 us; speedup 1.0000x reference)
//
#include <hip/hip_runtime.h>

#define BATCH 512
#define NNEG  2048
#define DIM   128
#define TB    32            // batch rows per block
#define TN    64            // tails per block
#define PADR  132           // padded row stride in floats (128 + 4) -> bank spread

// Block: 256 threads. Thread t: ts = t & 7 (tail lane), bs = t >> 3 (batch row 0..31).
// Each thread computes 8 outputs: tails {ts, 8+ts, ..., 56+ts} of its tail tile
// against batch row (b0 + bs). Query row lives in 128 VGPRs; tails come from LDS.
// Bank math (32 banks x 4B): row r starts at bank (r*132)%32 = (4r)%32.
//  - inner ds_read_b128: rows r = i*8+ts -> bank base 4*ts -> all 32 banks covered once.
//  - query reg load: rows bs (8 distinct per wave) -> bank base 4*bs -> conflict-free.

__global__ __launch_bounds__(256)
void transe_l1_kernel(const float* __restrict__ head,
                      const int*   __restrict__ relid,
                      const float* __restrict__ tail,
                      const float* __restrict__ relemb,
                      float* __restrict__ out) {
    __shared__ float ltail[TN * PADR];   // 33,792 B
    __shared__ float lq[TB * PADR];      // 16,896 B

    const int tid   = threadIdx.x;
    const int bx    = blockIdx.x;
    const int ttile = bx & 31;           // 32 tail tiles
    const int btile = bx >> 5;           // 16 batch tiles
    const int t0    = ttile * TN;
    const int b0    = btile * TB;

    // ---- stage queries: q = head[b] + relemb[relid[b]]  (32 rows x 32 float4) ----
    #pragma unroll
    for (int m = 0; m < 4; ++m) {
        int k   = tid + m * 256;         // 0..1023
        int row = k >> 5;                // 0..31
        int c4  = k & 31;                // 0..31
        int b   = b0 + row;
        int rid = relid[b];
        float4 h = *reinterpret_cast<const float4*>(&head[b * DIM + c4 * 4]);
        float4 r = *reinterpret_cast<const float4*>(&relemb[rid * DIM + c4 * 4]);
        float4 q;
        q.x = h.x + r.x; q.y = h.y + r.y; q.z = h.z + r.z; q.w = h.w + r.w;
        *reinterpret_cast<float4*>(&lq[row * PADR + c4 * 4]) = q;
    }

    // ---- stage tails (64 rows x 32 float4) ----
    #pragma unroll
    for (int m = 0; m < 8; ++m) {
        int k   = tid + m * 256;         // 0..2047
        int row = k >> 5;                // 0..63
        int c4  = k & 31;
        float4 tv = *reinterpret_cast<const float4*>(&tail[(t0 + row) * DIM + c4 * 4]);
        *reinterpret_cast<float4*>(&ltail[row * PADR + c4 * 4]) = tv;
    }

    __syncthreads();

    const int ts = tid & 7;
    const int bs = tid >> 3;

    // ---- pull query row into registers (128 VGPRs) ----
    float4 q[32];
    #pragma unroll
    for (int j = 0; j < 32; ++j) {
        q[j] = *reinterpret_cast<const float4*>(&lq[bs * PADR + j * 4]);
    }

    // ---- main compute: 8 tails per thread ----
    float res[8];
    #pragma unroll
    for (int i = 0; i < 8; ++i) {
        const float* tr = &ltail[(i * 8 + ts) * PADR];
        float sx = 0.f, sy = 0.f, sz = 0.f, sw = 0.f;  // 4 independent add chains
        #pragma unroll
        for (int j = 0; j < 32; ++j) {
            float4 tv = *reinterpret_cast<const float4*>(&tr[j * 4]);
            sx += fabsf(q[j].x - tv.x);
            sy += fabsf(q[j].y - tv.y);
            sz += fabsf(q[j].z - tv.z);
            sw += fabsf(q[j].w - tv.w);
        }
        res[i] = -((sx + sy) + (sz + sw));
    }

    // ---- write: lanes ts=0..7 give 32B contiguous segments per 8-lane group ----
    const int b = b0 + bs;
    #pragma unroll
    for (int i = 0; i < 8; ++i) {
        out[b * NNEG + t0 + i * 8 + ts] = res[i];
    }
}

extern "C" void kernel_launch(void* const* d_in, const int* in_sizes, int n_in,
                              void* d_out, int out_size, void* d_ws, size_t ws_size,
                              hipStream_t stream) {
    const float* head   = (const float*)d_in[0];
    const int*   relid  = (const int*)d_in[1];
    const float* tail   = (const float*)d_in[2];
    const float* relemb = (const float*)d_in[3];
    float*       out    = (float*)d_out;

    dim3 grid((BATCH / TB) * (NNEG / TN));   // 16 * 32 = 512 blocks
    dim3 block(256);
    transe_l1_kernel<<<grid, block, 0, stream>>>(head, relid, tail, relemb, out);
}